// Round 15
// baseline (329.169 us; speedup 1.0000x reference)
//
#include <hip/hip_runtime.h>

typedef __attribute__((ext_vector_type(4))) float fx4;
typedef __attribute__((ext_vector_type(8))) short s16x8;
typedef __attribute__((ext_vector_type(2))) unsigned long long u64x2;

#define SEQ   2048
#define DM    1024
#define BSZ   4
#define ROWS  (BSZ*SEQ)   /* 8192 */
#define CHUNK 64
#define NCH   (SEQ/CHUNK) /* 32 */

__device__ __forceinline__ unsigned short f2bf(float f){
  unsigned u = __builtin_bit_cast(unsigned, f);
  u = u + 0x7FFFu + ((u >> 16) & 1u);
  return (unsigned short)(u >> 16);
}
__device__ __forceinline__ float bf2f(unsigned short u){
  return __builtin_bit_cast(float, ((unsigned)u) << 16);
}

// f32 -> OCP e4m3fn (software path, used only in transpose_f8).
__device__ __forceinline__ unsigned char f2fp8(float x){
  unsigned u = __builtin_bit_cast(unsigned, x);
  unsigned s = (u >> 24) & 0x80u;
  float ax = __builtin_fabsf(x);
  if (ax >= 448.f) return (unsigned char)(s | 0x7Eu);
  if (ax < 0.015625f){
    int m = (int)(ax * 512.f + 0.5f);
    return (unsigned char)(s | (unsigned)m);
  }
  unsigned b = __builtin_bit_cast(unsigned, ax);
  b += 0x0007FFFFu + ((b >> 20) & 1u);
  unsigned e = (b >> 23) - 127u + 7u;
  unsigned m = (b >> 20) & 7u;
  return (unsigned char)(s | (e << 3) | m);
}

// HW pack: 4 f32 -> 4 fp8 bytes in one int.
__device__ __forceinline__ int pk4_fp8(float a, float b, float c, float d){
  int lo = __builtin_amdgcn_cvt_pk_fp8_f32(a, b, 0, false);
  return  __builtin_amdgcn_cvt_pk_fp8_f32(c, d, lo, true);
}

// fast tanh-gelu: 0.5x(1+tanh(u)) == x*sigmoid(2u)
__device__ __forceinline__ float gelu_f(float x){
  float u = 0.7978845608028654f * (x + 0.044715f * x*x*x);
  return x / (1.0f + __expf(-2.0f*u));
}

__device__ __forceinline__ void gload_lds16(const void* g, void* l){
  __builtin_amdgcn_global_load_lds(
      (__attribute__((address_space(1))) void*)g,
      (__attribute__((address_space(3))) void*)l, 16, 0, 0);
}

// non-scaled fp8 MFMA (bf16 rate, 2-VGPR operands). B holds W*64.
__device__ __forceinline__ fx4 mfma_fp8(unsigned long long a, unsigned long long b, fx4 c){
  return __builtin_amdgcn_mfma_f32_16x16x32_fp8_fp8((long)a, (long)b, c, 0, 0, 0);
}

// ---------------- transpose fp32 [R][C] -> bf16 [C][R], batched ----------------
__global__ __launch_bounds__(256) void transpose_k(const float* __restrict__ in,
    unsigned short* __restrict__ out, int R, int C, long long ibs, long long obs){
  __shared__ float tile[32][33];
  in  += (long long)blockIdx.z * ibs;
  out += (long long)blockIdx.z * obs;
  int c0 = blockIdx.x*32, r0 = blockIdx.y*32;
  int tx = threadIdx.x, ty = threadIdx.y;
  #pragma unroll
  for (int i=0;i<4;i++)
    tile[ty+8*i][tx] = in[(long long)(r0+ty+8*i)*C + c0+tx];
  __syncthreads();
  #pragma unroll
  for (int i=0;i<4;i++)
    out[(long long)(c0+ty+8*i)*R + r0+tx] = f2bf(tile[tx][ty+8*i]);
}

// ---------------- transpose fp32 [R][C] -> fp8 [C][R], value*64 ----------------
__global__ __launch_bounds__(256) void transpose_f8(const float* __restrict__ in,
    unsigned char* __restrict__ out, int R, int C){
  __shared__ float tile[32][33];
  int c0 = blockIdx.x*32, r0 = blockIdx.y*32;
  int tx = threadIdx.x, ty = threadIdx.y;
  #pragma unroll
  for (int i=0;i<4;i++)
    tile[ty+8*i][tx] = in[(long long)(r0+ty+8*i)*C + c0+tx];
  __syncthreads();
  #pragma unroll
  for (int i=0;i<4;i++)
    out[(long long)(c0+ty+8*i)*R + r0+tx] = f2fp8(tile[tx][ty+8*i] * 64.f);
}

// ---------------- LayerNorm over D=1024, one block per row (bf16 out) ----------------
__global__ __launch_bounds__(256) void ln_rows(const float* __restrict__ x,
    const float* __restrict__ g, const float* __restrict__ b,
    unsigned short* __restrict__ out){
  int row = blockIdx.x, t = threadIdx.x;
  const fx4* xr = (const fx4*)(x + (long long)row*DM);
  fx4 v = xr[t];
  float s  = v[0]+v[1]+v[2]+v[3];
  float s2 = v[0]*v[0]+v[1]*v[1]+v[2]*v[2]+v[3]*v[3];
  #pragma unroll
  for (int o=32;o;o>>=1){ s += __shfl_down(s,o); s2 += __shfl_down(s2,o); }
  __shared__ float red[8];
  int lane = t & 63, wid = t >> 6;
  if (lane==0){ red[wid]=s; red[4+wid]=s2; }
  __syncthreads();
  s  = red[0]+red[1]+red[2]+red[3];
  s2 = red[4]+red[5]+red[6]+red[7];
  float m  = s * (1.0f/DM);
  float rs = rsqrtf(s2*(1.0f/DM) - m*m + 1e-5f);
  const fx4 gv = ((const fx4*)g)[t], bv = ((const fx4*)b)[t];
  ushort4 pk;
  pk.x = f2bf((v[0]-m)*rs*gv[0] + bv[0]);
  pk.y = f2bf((v[1]-m)*rs*gv[1] + bv[1]);
  pk.z = f2bf((v[2]-m)*rs*gv[2] + bv[2]);
  pk.w = f2bf((v[3]-m)*rs*gv[3] + bv[3]);
  *(ushort4*)(out + (long long)row*DM + t*4) = pk;
}

// ---------------- LayerNorm, fp8 out (HW cvt_pk) ----------------
__global__ __launch_bounds__(256) void ln_rows_f8(const float* __restrict__ x,
    const float* __restrict__ g, const float* __restrict__ b,
    unsigned char* __restrict__ out){
  int row = blockIdx.x, t = threadIdx.x;
  const fx4* xr = (const fx4*)(x + (long long)row*DM);
  fx4 v = xr[t];
  float s  = v[0]+v[1]+v[2]+v[3];
  float s2 = v[0]*v[0]+v[1]*v[1]+v[2]*v[2]+v[3]*v[3];
  #pragma unroll
  for (int o=32;o;o>>=1){ s += __shfl_down(s,o); s2 += __shfl_down(s2,o); }
  __shared__ float red[8];
  int lane = t & 63, wid = t >> 6;
  if (lane==0){ red[wid]=s; red[4+wid]=s2; }
  __syncthreads();
  s  = red[0]+red[1]+red[2]+red[3];
  s2 = red[4]+red[5]+red[6]+red[7];
  float m  = s * (1.0f/DM);
  float rs = rsqrtf(s2*(1.0f/DM) - m*m + 1e-5f);
  const fx4 gv = ((const fx4*)g)[t], bv = ((const fx4*)b)[t];
  int pk = pk4_fp8((v[0]-m)*rs*gv[0] + bv[0], (v[1]-m)*rs*gv[1] + bv[1],
                   (v[2]-m)*rs*gv[2] + bv[2], (v[3]-m)*rs*gv[3] + bv[3]);
  *(int*)(out + (long long)row*DM + t*4) = pk;
}

// ---------------- scan pass 1: per-chunk carries (P in bf16) ----------------
__global__ __launch_bounds__(256) void scan_carry(const unsigned short* __restrict__ P,
    const float* __restrict__ w_row, const float* __restrict__ dcol,
    const float* __restrict__ drow, float* __restrict__ carry){
  int g = blockIdx.x*4 + (threadIdx.x>>6);
  int lane = threadIdx.x & 63;
  int chunk = g & (NCH-1); int bh = g >> 5; int h = bh & 15; int b = bh >> 4;
  float draw = (h<8) ? dcol[h] : drow[h-8];
  float d = powf(fminf(fmaxf(draw,0.9f),1.0f), 0.25f);
  float c = 0.f;
  const unsigned short* p = P + ((long long)(b*SEQ + chunk*CHUNK))*DM + h*64 + lane;
  const float* wr = w_row + (h>=8 ? (h-8)*SEQ + chunk*CHUNK : 0);
  #pragma unroll 4
  for (int i=0;i<CHUNK;i++){
    float a = bf2f(p[(long long)i*DM]);
    if (h>=8) a *= wr[i];
    c = fmaf(d, c, a);
  }
  carry[((long long)(bh*64 + lane))*NCH + chunk] = c;
}

// ---------------- scan pass 2: apply carries, emit mix (bf16) ----------------
__global__ __launch_bounds__(256) void scan_final(const unsigned short* __restrict__ P,
    const float* __restrict__ w_col, const float* __restrict__ b_col,
    const float* __restrict__ w_row, const float* __restrict__ b_row,
    const float* __restrict__ dcol, const float* __restrict__ drow,
    const float* __restrict__ carry, unsigned short* __restrict__ mix){
  int g = blockIdx.x*4 + (threadIdx.x>>6);
  int lane = threadIdx.x & 63;
  int chunk = g & (NCH-1); int bh = g >> 5; int h = bh & 15; int b = bh >> 4;
  float draw = (h<8) ? dcol[h] : drow[h-8];
  float d = powf(fminf(fmaxf(draw,0.9f),1.0f), 0.25f);
  float dL = d;
  #pragma unroll
  for (int i=0;i<6;i++) dL *= dL;        // d^64
  const float* cr = carry + ((long long)(bh*64 + lane))*NCH;
  float c = 0.f;
  for (int j=0;j<chunk;j++) c = fmaf(dL, c, cr[j]);   // carry-in
  const unsigned short* p = P + ((long long)(b*SEQ + chunk*CHUNK))*DM + h*64 + lane;
  unsigned short* mo = mix + ((long long)(b*SEQ + chunk*CHUNK))*DM + h*64 + lane;
  int t0 = chunk*CHUNK;
  #pragma unroll 4
  for (int i=0;i<CHUNK;i++){
    int t = t0 + i;
    float a = bf2f(p[(long long)i*DM]);
    float o;
    if (h<8){
      c = fmaf(d, c, a);
      o = w_col[h*SEQ + t]*c + b_col[h*SEQ + t];
    } else {
      a *= w_row[(h-8)*SEQ + t];
      c = fmaf(d, c, a);
      o = c + b_row[(h-8)*SEQ + t];
    }
    mo[(long long)i*DM] = f2bf(o);
  }
}

// ---------------- 128x128 bf16 GEMM, single 32KB buffer, BK=64 (r11 verified) ----------------
// (r14's BK=32 triple-buffer port regressed ~12us each: per-step overhead
// doubled with halved MFMA. Reverted.)
// EPI 1: fp32+bias+res  3: bf16
template<int EPI, int K>
__global__ __launch_bounds__(256) void gemm_bt(const unsigned short* __restrict__ A,
    const unsigned short* __restrict__ Bt, int N,
    const float* __restrict__ bias, const float* __restrict__ res,
    float* __restrict__ outf, unsigned short* __restrict__ outb){
  __shared__ __align__(16) unsigned short lds[16384];   // 32KB
  const int tid = threadIdx.x;
  const int l = tid & 63;
  const int w = tid >> 6;
  const int wr = w >> 1, wc = w & 1;
  const long long row0 = (long long)blockIdx.x * 128;
  const long long col0 = (long long)blockIdx.y * 128;

  fx4 acc[4][4] = {};

  const unsigned short* gA[4];
  const unsigned short* gB[4];
  int lslot[4];
  #pragma unroll
  for (int i=0;i<4;i++){
    int slot = w*256 + i*64 + l;
    int r = slot >> 3;
    int qs = slot & 7;
    int c = (qs ^ (r & 7)) << 3;
    gA[i] = A  + (row0 + r)*(long long)K + c;
    gB[i] = Bt + (col0 + r)*(long long)K + c;
    lslot[i] = slot*8;
  }
  int aoff[2][4], boff[2][4];
  #pragma unroll
  for (int kk=0;kk<2;kk++){
    #pragma unroll
    for (int m=0;m<4;m++){
      int r  = wr*64 + m*16 + (l&15);
      int q  = (kk*4 + (l>>4)) ^ (r&7);
      aoff[kk][m] = r*64 + q*8;
      int r2 = wc*64 + m*16 + (l&15);
      int q2 = (kk*4 + (l>>4)) ^ (r2&7);
      boff[kk][m] = 8192 + r2*64 + q2*8;
    }
  }

  const int nsteps = K >> 6;
  for (int s = 0; s < nsteps; ++s){
    #pragma unroll
    for (int i=0;i<4;i++){
      gload_lds16(gA[i], &lds[lslot[i]]);
      gload_lds16(gB[i], &lds[8192 + lslot[i]]);
      gA[i] += 64; gB[i] += 64;
    }
    __syncthreads();
    #pragma unroll
    for (int kk=0;kk<2;kk++){
      s16x8 af[4], bfr[4];
      #pragma unroll
      for (int m=0;m<4;m++) af[m]  = *(const s16x8*)&lds[aoff[kk][m]];
      #pragma unroll
      for (int n=0;n<4;n++) bfr[n] = *(const s16x8*)&lds[boff[kk][n]];
      #pragma unroll
      for (int m=0;m<4;m++)
        #pragma unroll
        for (int n=0;n<4;n++)
          acc[m][n] = __builtin_amdgcn_mfma_f32_16x16x32_bf16(af[m], bfr[n], acc[m][n], 0, 0, 0);
    }
    __syncthreads();
  }

  float* lf = (float*)lds;              // [32][132]
  const int lg = l >> 4, lc = l & 15;
  #pragma unroll
  for (int g=0; g<4; ++g){
    if (wr == (g>>1)){
      #pragma unroll
      for (int mm=0; mm<2; ++mm){
        const int m = (g&1)*2 + mm;
        int lrow = mm*16 + lg*4;
        #pragma unroll
        for (int n=0;n<4;n++){
          int col = wc*64 + n*16 + lc;
          #pragma unroll
          for (int rg=0;rg<4;rg++)
            lf[(lrow+rg)*132 + col] = acc[m][n][rg];
        }
      }
    }
    __syncthreads();
    #pragma unroll
    for (int j=0;j<4;j++){
      int flat = j*256 + tid;
      int lrow = flat >> 5, c4 = flat & 31;
      long long grow = row0 + g*32 + lrow;
      long long gcol = col0 + c4*4;
      fx4 v = *(fx4*)&lf[lrow*132 + c4*4];
      fx4 bv = *(const fx4*)&bias[gcol];
      v = v + bv;
      long long idx = grow*(long long)N + gcol;
      if constexpr (EPI==1){
        fx4 rv = *(const fx4*)&res[idx];
        v = v + rv;
        *(fx4*)&outf[idx] = v;
      } else {
        ushort4 pk;
        pk.x = f2bf(v[0]); pk.y = f2bf(v[1]);
        pk.z = f2bf(v[2]); pk.w = f2bf(v[3]);
        *(ushort4*)&outb[idx] = pk;
      }
    }
    __syncthreads();
  }
}

// ---------------- 128x256 FP8 GEMM, wave-tile 128x64, triple-buffer vmcnt(6) ----------------
// r14 PMC closed the model: 128x128/4-wave fp8 is LDS-traffic-bound
// (32KB rd + 16KB wr per K-step = ~384cy vs 155cy MFMA -> MfmaUtil 40%).
// Fix: wave-tile 128x64 (acc[8][4]), 4 waves = 1x4 over N -> block 128x256.
// Per-lane LDS reads 128B->192B while MFMA 32->64: FLOP/LDS-byte x1.33.
// Pipeline = r13's validated counted-vmcnt triple buffer (6 loads/stage).
// Swizzle pair (r>>1)&3 on 64B rows (r13: 0 conflicts). B holds W*64.
// EPI 1: fp32+bias+res  2: fp8(gelu(acc/64+bias))
template<int EPI, int K>
__global__ __launch_bounds__(256) void gemm_f8(const unsigned char* __restrict__ A,
    const unsigned char* __restrict__ Bt, int N,
    const float* __restrict__ bias, const float* __restrict__ res,
    float* __restrict__ outf, unsigned char* __restrict__ outb){
  __shared__ __align__(16) unsigned char lds[73728];  // 3 x (A 8KB + B 16KB)
  const int tid = threadIdx.x;
  const int l = tid & 63;
  const int wcn = tid >> 6;              // wave = N-slice 0..3
  const long long row0 = (long long)blockIdx.x * 128;
  const long long col0 = (long long)blockIdx.y * 256;

  fx4 acc[8][4] = {};

  // A staging: 8KB tile, 512 slots x 16B; 2 slots/thread
  const unsigned char* gA[2];
  int lslotA[2];
  #pragma unroll
  for (int i=0;i<2;i++){
    int slot = wcn*128 + i*64 + l;       // 0..511
    int r = slot >> 2;                   // row 0..127 (64B rows)
    int q = slot & 3;
    int c = (q ^ ((r >> 1) & 3)) << 4;
    gA[i] = A + (row0 + r)*(long long)K + c;
    lslotA[i] = slot*16;
  }
  // B staging: 16KB tile, 1024 slots x 16B; 4 slots/thread
  const unsigned char* gB[4];
  int lslotB[4];
  #pragma unroll
  for (int i=0;i<4;i++){
    int slot = wcn*256 + i*64 + l;       // 0..1023
    int r = slot >> 2;                   // row 0..255
    int q = slot & 3;
    int c = (q ^ ((r >> 1) & 3)) << 4;
    gB[i] = Bt + (col0 + r)*(long long)K + c;
    lslotB[i] = 8192 + slot*16;
  }
  const int lg = l >> 4, l15 = l & 15;
  int aoff[8], boff[4];
  #pragma unroll
  for (int m=0;m<8;m++){
    int r = m*16 + l15;                  // all waves read all 128 A rows
    aoff[m] = r*64 + ((lg ^ ((r >> 1) & 3)) << 4);
  }
  #pragma unroll
  for (int n=0;n<4;n++){
    int r2 = wcn*64 + n*16 + l15;        // wave's own 64-row B slice
    boff[n] = 8192 + r2*64 + ((lg ^ ((r2 >> 1) & 3)) << 4);
  }
  auto STAGE = [&](int bufoff){
    #pragma unroll
    for (int i=0;i<2;i++){
      gload_lds16(gA[i], &lds[bufoff + lslotA[i]]);
      gA[i] += 64;
    }
    #pragma unroll
    for (int i=0;i<4;i++){
      gload_lds16(gB[i], &lds[bufoff + lslotB[i]]);
      gB[i] += 64;
    }
  };

  const int nsteps = K >> 6;
  STAGE(0);
  STAGE(24576);

  int curoff = 0;
  for (int s = 0; s < nsteps; ++s){
    if (s + 1 < nsteps) asm volatile("s_waitcnt vmcnt(6)" ::: "memory");
    else                asm volatile("s_waitcnt vmcnt(0)" ::: "memory");
    __builtin_amdgcn_sched_barrier(0);
    __builtin_amdgcn_s_barrier();
    __builtin_amdgcn_sched_barrier(0);
    u64x2 a2[8], b2[4];
    #pragma unroll
    for (int m=0;m<8;m++) a2[m] = *(const u64x2*)&lds[curoff + aoff[m]];
    #pragma unroll
    for (int n=0;n<4;n++) b2[n] = *(const u64x2*)&lds[curoff + boff[n]];
    if (s + 2 < nsteps){
      int nb = curoff + 49152; if (nb >= 73728) nb -= 73728;   // buf (s+2)%3
      STAGE(nb);
    }
    #pragma unroll
    for (int m=0;m<8;m++)
      #pragma unroll
      for (int n=0;n<4;n++)
        acc[m][n] = mfma_fp8(a2[m][0], b2[n][0], acc[m][n]);
    #pragma unroll
    for (int m=0;m<8;m++)
      #pragma unroll
      for (int n=0;n<4;n++)
        acc[m][n] = mfma_fp8(a2[m][1], b2[n][1], acc[m][n]);
    curoff += 24576; if (curoff == 73728) curoff = 0;
  }
  __syncthreads();

  // epilogue: 4 row-groups of 32; every wave writes its 64-col slice
  float* lf = (float*)lds;              // [32][260] fp32 = 33.3KB
  #pragma unroll
  for (int g=0; g<4; ++g){
    #pragma unroll
    for (int mm=0; mm<2; ++mm){
      const int m = g*2 + mm;
      int lrow = mm*16 + lg*4;
      #pragma unroll
      for (int n=0;n<4;n++){
        int col = wcn*64 + n*16 + l15;
        #pragma unroll
        for (int rg=0;rg<4;rg++)
          lf[(lrow+rg)*260 + col] = acc[m][n][rg];
      }
    }
    __syncthreads();
    #pragma unroll
    for (int j=0;j<8;j++){
      int flat = j*256 + tid;            // 0..2047 = 32 rows x 64 fx4
      int lrow = flat >> 6, c4 = flat & 63;
      long long grow = row0 + g*32 + lrow;
      long long gcol = col0 + c4*4;
      fx4 v = *(fx4*)&lf[lrow*260 + c4*4];
      fx4 bv2 = *(const fx4*)&bias[gcol];
      v = v * 0.015625f + bv2;          // undo W*64
      long long idx = grow*(long long)N + gcol;
      if constexpr (EPI==1){
        fx4 rv = *(const fx4*)&res[idx];
        v = v + rv;
        *(fx4*)&outf[idx] = v;
      } else {
        *(int*)&outb[idx] = pk4_fp8(gelu_f(v[0]), gelu_f(v[1]),
                                    gelu_f(v[2]), gelu_f(v[3]));
      }
    }
    __syncthreads();
  }
}

// ---------------- host ----------------
extern "C" void kernel_launch(void* const* d_in, const int* in_sizes, int n_in,
                              void* d_out, int out_size, void* d_ws, size_t ws_size,
                              hipStream_t stream){
  const float* x    = (const float*)d_in[0];
  const float* g1   = (const float*)d_in[1];
  const float* b1   = (const float*)d_in[2];
  const float* g2   = (const float*)d_in[3];
  const float* b2   = (const float*)d_in[4];
  const float* Wp   = (const float*)d_in[5];
  const float* bp   = (const float*)d_in[6];
  const float* Wo   = (const float*)d_in[7];
  const float* bo   = (const float*)d_in[8];
  const float* w_col= (const float*)d_in[9];
  const float* b_col= (const float*)d_in[10];
  const float* w_row= (const float*)d_in[11];
  const float* b_row= (const float*)d_in[12];
  const float* dcol = (const float*)d_in[13];
  const float* drow = (const float*)d_in[14];
  const float* W1   = (const float*)d_in[15];
  const float* c1   = (const float*)d_in[16];
  const float* W2   = (const float*)d_in[17];
  const float* c2   = (const float*)d_in[18];
  float* out = (float*)d_out;

  char* ws = (char*)d_ws;
  const size_t MB = 1024*1024;
  if (ws_size < 101*MB) return;
  unsigned short* Wpt  = (unsigned short*)(ws + 0);      // 128KB bf16
  unsigned short* Wot  = (unsigned short*)(ws + 2*MB);   // 2MB bf16
  unsigned char*  W1t8 = (unsigned char*)(ws + 4*MB);    // 4MB fp8 (x64)
  unsigned char*  W2t8 = (unsigned char*)(ws + 12*MB);   // 4MB fp8 (x64)
  unsigned short* h    = (unsigned short*)(ws + 20*MB);  // 16MB bf16; later yln8
  unsigned char*  yln8 = (unsigned char*)(ws + 20*MB);   // 8MB fp8 (h dead)
  unsigned short* P    = (unsigned short*)(ws + 36*MB);  // 16MB bf16
  unsigned char*  U8   = (unsigned char*)(ws + 36*MB);   // 32MB fp8 (P/mix dead)
  unsigned short* mix  = (unsigned short*)(ws + 68*MB);  // 16MB bf16
  float*          carry= (float*)(ws + 84*MB);

  dim3 tb(32,8);
  transpose_k <<<dim3(2,32,16),  tb, 0, stream>>>(Wp, Wpt, 1024,   64, 65536LL, 65536LL);
  transpose_k <<<dim3(32,32,1),  tb, 0, stream>>>(Wo, Wot, 1024, 1024, 0LL, 0LL);
  transpose_f8<<<dim3(128,32,1), tb, 0, stream>>>(W1, W1t8, 1024, 4096);
  transpose_f8<<<dim3(32,128,1), tb, 0, stream>>>(W2, W2t8, 4096, 1024);

  ln_rows<<<dim3(ROWS), dim3(256), 0, stream>>>(x, g1, b1, h);
  gemm_bt<3,1024><<<dim3(64,8),  dim3(256), 0, stream>>>(h,   Wpt, 1024, bp, nullptr, nullptr, P);
  scan_carry<<<dim3(512), dim3(256), 0, stream>>>(P, w_row, dcol, drow, carry);
  scan_final<<<dim3(512), dim3(256), 0, stream>>>(P, w_col, b_col, w_row, b_row, dcol, drow, carry, mix);
  gemm_bt<1,1024><<<dim3(64,8),  dim3(256), 0, stream>>>(mix, Wot, 1024, bo, x, out, nullptr);
  ln_rows_f8<<<dim3(ROWS), dim3(256), 0, stream>>>(out, g2, b2, yln8);
  gemm_f8<2,1024><<<dim3(64,16), dim3(256), 0, stream>>>(yln8, W1t8, 4096, c1, nullptr, nullptr, U8);
  gemm_f8<1,4096><<<dim3(64,4),  dim3(256), 0, stream>>>(U8,  W2t8, 1024, c2, out, out, nullptr);
}

// Round 16
// 264.592 us; speedup vs baseline: 1.2441x; 1.2441x over previous
//
#include <hip/hip_runtime.h>

typedef __attribute__((ext_vector_type(4))) float fx4;
typedef __attribute__((ext_vector_type(8))) short s16x8;
typedef __attribute__((ext_vector_type(2))) unsigned long long u64x2;

#define SEQ   2048
#define DM    1024
#define BSZ   4
#define ROWS  (BSZ*SEQ)   /* 8192 */
#define CHUNK 64
#define NCH   (SEQ/CHUNK) /* 32 */

__device__ __forceinline__ unsigned short f2bf(float f){
  unsigned u = __builtin_bit_cast(unsigned, f);
  u = u + 0x7FFFu + ((u >> 16) & 1u);
  return (unsigned short)(u >> 16);
}
__device__ __forceinline__ float bf2f(unsigned short u){
  return __builtin_bit_cast(float, ((unsigned)u) << 16);
}

// f32 -> OCP e4m3fn (software path, used only in transpose_f8).
__device__ __forceinline__ unsigned char f2fp8(float x){
  unsigned u = __builtin_bit_cast(unsigned, x);
  unsigned s = (u >> 24) & 0x80u;
  float ax = __builtin_fabsf(x);
  if (ax >= 448.f) return (unsigned char)(s | 0x7Eu);
  if (ax < 0.015625f){
    int m = (int)(ax * 512.f + 0.5f);
    return (unsigned char)(s | (unsigned)m);
  }
  unsigned b = __builtin_bit_cast(unsigned, ax);
  b += 0x0007FFFFu + ((b >> 20) & 1u);
  unsigned e = (b >> 23) - 127u + 7u;
  unsigned m = (b >> 20) & 7u;
  return (unsigned char)(s | (e << 3) | m);
}

// HW pack: 4 f32 -> 4 fp8 bytes in one int.
__device__ __forceinline__ int pk4_fp8(float a, float b, float c, float d){
  int lo = __builtin_amdgcn_cvt_pk_fp8_f32(a, b, 0, false);
  return  __builtin_amdgcn_cvt_pk_fp8_f32(c, d, lo, true);
}

// fast tanh-gelu: 0.5x(1+tanh(u)) == x*sigmoid(2u)
__device__ __forceinline__ float gelu_f(float x){
  float u = 0.7978845608028654f * (x + 0.044715f * x*x*x);
  return x / (1.0f + __expf(-2.0f*u));
}

__device__ __forceinline__ void gload_lds16(const void* g, void* l){
  __builtin_amdgcn_global_load_lds(
      (__attribute__((address_space(1))) void*)g,
      (__attribute__((address_space(3))) void*)l, 16, 0, 0);
}

// non-scaled fp8 MFMA (bf16 rate, 2-VGPR operands). B holds W*64.
__device__ __forceinline__ fx4 mfma_fp8(unsigned long long a, unsigned long long b, fx4 c){
  return __builtin_amdgcn_mfma_f32_16x16x32_fp8_fp8((long)a, (long)b, c, 0, 0, 0);
}

// ---------------- transpose fp32 [R][C] -> bf16 [C][R], batched ----------------
__global__ __launch_bounds__(256) void transpose_k(const float* __restrict__ in,
    unsigned short* __restrict__ out, int R, int C, long long ibs, long long obs){
  __shared__ float tile[32][33];
  in  += (long long)blockIdx.z * ibs;
  out += (long long)blockIdx.z * obs;
  int c0 = blockIdx.x*32, r0 = blockIdx.y*32;
  int tx = threadIdx.x, ty = threadIdx.y;
  #pragma unroll
  for (int i=0;i<4;i++)
    tile[ty+8*i][tx] = in[(long long)(r0+ty+8*i)*C + c0+tx];
  __syncthreads();
  #pragma unroll
  for (int i=0;i<4;i++)
    out[(long long)(c0+ty+8*i)*R + r0+tx] = f2bf(tile[tx][ty+8*i]);
}

// ---------------- transpose fp32 [R][C] -> fp8 [C][R], value*64 ----------------
__global__ __launch_bounds__(256) void transpose_f8(const float* __restrict__ in,
    unsigned char* __restrict__ out, int R, int C){
  __shared__ float tile[32][33];
  int c0 = blockIdx.x*32, r0 = blockIdx.y*32;
  int tx = threadIdx.x, ty = threadIdx.y;
  #pragma unroll
  for (int i=0;i<4;i++)
    tile[ty+8*i][tx] = in[(long long)(r0+ty+8*i)*C + c0+tx];
  __syncthreads();
  #pragma unroll
  for (int i=0;i<4;i++)
    out[(long long)(c0+ty+8*i)*R + r0+tx] = f2fp8(tile[tx][ty+8*i] * 64.f);
}

// ---------------- LayerNorm over D=1024, one block per row (bf16 out) ----------------
__global__ __launch_bounds__(256) void ln_rows(const float* __restrict__ x,
    const float* __restrict__ g, const float* __restrict__ b,
    unsigned short* __restrict__ out){
  int row = blockIdx.x, t = threadIdx.x;
  const fx4* xr = (const fx4*)(x + (long long)row*DM);
  fx4 v = xr[t];
  float s  = v[0]+v[1]+v[2]+v[3];
  float s2 = v[0]*v[0]+v[1]*v[1]+v[2]*v[2]+v[3]*v[3];
  #pragma unroll
  for (int o=32;o;o>>=1){ s += __shfl_down(s,o); s2 += __shfl_down(s2,o); }
  __shared__ float red[8];
  int lane = t & 63, wid = t >> 6;
  if (lane==0){ red[wid]=s; red[4+wid]=s2; }
  __syncthreads();
  s  = red[0]+red[1]+red[2]+red[3];
  s2 = red[4]+red[5]+red[6]+red[7];
  float m  = s * (1.0f/DM);
  float rs = rsqrtf(s2*(1.0f/DM) - m*m + 1e-5f);
  const fx4 gv = ((const fx4*)g)[t], bv = ((const fx4*)b)[t];
  ushort4 pk;
  pk.x = f2bf((v[0]-m)*rs*gv[0] + bv[0]);
  pk.y = f2bf((v[1]-m)*rs*gv[1] + bv[1]);
  pk.z = f2bf((v[2]-m)*rs*gv[2] + bv[2]);
  pk.w = f2bf((v[3]-m)*rs*gv[3] + bv[3]);
  *(ushort4*)(out + (long long)row*DM + t*4) = pk;
}

// ---------------- LayerNorm, fp8 out (HW cvt_pk) ----------------
__global__ __launch_bounds__(256) void ln_rows_f8(const float* __restrict__ x,
    const float* __restrict__ g, const float* __restrict__ b,
    unsigned char* __restrict__ out){
  int row = blockIdx.x, t = threadIdx.x;
  const fx4* xr = (const fx4*)(x + (long long)row*DM);
  fx4 v = xr[t];
  float s  = v[0]+v[1]+v[2]+v[3];
  float s2 = v[0]*v[0]+v[1]*v[1]+v[2]*v[2]+v[3]*v[3];
  #pragma unroll
  for (int o=32;o;o>>=1){ s += __shfl_down(s,o); s2 += __shfl_down(s2,o); }
  __shared__ float red[8];
  int lane = t & 63, wid = t >> 6;
  if (lane==0){ red[wid]=s; red[4+wid]=s2; }
  __syncthreads();
  s  = red[0]+red[1]+red[2]+red[3];
  s2 = red[4]+red[5]+red[6]+red[7];
  float m  = s * (1.0f/DM);
  float rs = rsqrtf(s2*(1.0f/DM) - m*m + 1e-5f);
  const fx4 gv = ((const fx4*)g)[t], bv = ((const fx4*)b)[t];
  int pk = pk4_fp8((v[0]-m)*rs*gv[0] + bv[0], (v[1]-m)*rs*gv[1] + bv[1],
                   (v[2]-m)*rs*gv[2] + bv[2], (v[3]-m)*rs*gv[3] + bv[3]);
  *(int*)(out + (long long)row*DM + t*4) = pk;
}

// ---------------- scan pass 1: per-chunk carries (P in bf16) ----------------
__global__ __launch_bounds__(256) void scan_carry(const unsigned short* __restrict__ P,
    const float* __restrict__ w_row, const float* __restrict__ dcol,
    const float* __restrict__ drow, float* __restrict__ carry){
  int g = blockIdx.x*4 + (threadIdx.x>>6);
  int lane = threadIdx.x & 63;
  int chunk = g & (NCH-1); int bh = g >> 5; int h = bh & 15; int b = bh >> 4;
  float draw = (h<8) ? dcol[h] : drow[h-8];
  float d = powf(fminf(fmaxf(draw,0.9f),1.0f), 0.25f);
  float c = 0.f;
  const unsigned short* p = P + ((long long)(b*SEQ + chunk*CHUNK))*DM + h*64 + lane;
  const float* wr = w_row + (h>=8 ? (h-8)*SEQ + chunk*CHUNK : 0);
  #pragma unroll 4
  for (int i=0;i<CHUNK;i++){
    float a = bf2f(p[(long long)i*DM]);
    if (h>=8) a *= wr[i];
    c = fmaf(d, c, a);
  }
  carry[((long long)(bh*64 + lane))*NCH + chunk] = c;
}

// ---------------- scan pass 2: apply carries, emit mix (bf16) ----------------
__global__ __launch_bounds__(256) void scan_final(const unsigned short* __restrict__ P,
    const float* __restrict__ w_col, const float* __restrict__ b_col,
    const float* __restrict__ w_row, const float* __restrict__ b_row,
    const float* __restrict__ dcol, const float* __restrict__ drow,
    const float* __restrict__ carry, unsigned short* __restrict__ mix){
  int g = blockIdx.x*4 + (threadIdx.x>>6);
  int lane = threadIdx.x & 63;
  int chunk = g & (NCH-1); int bh = g >> 5; int h = bh & 15; int b = bh >> 4;
  float draw = (h<8) ? dcol[h] : drow[h-8];
  float d = powf(fminf(fmaxf(draw,0.9f),1.0f), 0.25f);
  float dL = d;
  #pragma unroll
  for (int i=0;i<6;i++) dL *= dL;        // d^64
  const float* cr = carry + ((long long)(bh*64 + lane))*NCH;
  float c = 0.f;
  for (int j=0;j<chunk;j++) c = fmaf(dL, c, cr[j]);   // carry-in
  const unsigned short* p = P + ((long long)(b*SEQ + chunk*CHUNK))*DM + h*64 + lane;
  unsigned short* mo = mix + ((long long)(b*SEQ + chunk*CHUNK))*DM + h*64 + lane;
  int t0 = chunk*CHUNK;
  #pragma unroll 4
  for (int i=0;i<CHUNK;i++){
    int t = t0 + i;
    float a = bf2f(p[(long long)i*DM]);
    float o;
    if (h<8){
      c = fmaf(d, c, a);
      o = w_col[h*SEQ + t]*c + b_col[h*SEQ + t];
    } else {
      a *= w_row[(h-8)*SEQ + t];
      c = fmaf(d, c, a);
      o = c + b_row[(h-8)*SEQ + t];
    }
    mo[(long long)i*DM] = f2bf(o);
  }
}

// ---------------- 128x128 bf16 GEMM, single 32KB buffer, BK=64 (r11 verified) ----------------
// EPI 1: fp32+bias+res  3: bf16
template<int EPI, int K>
__global__ __launch_bounds__(256) void gemm_bt(const unsigned short* __restrict__ A,
    const unsigned short* __restrict__ Bt, int N,
    const float* __restrict__ bias, const float* __restrict__ res,
    float* __restrict__ outf, unsigned short* __restrict__ outb){
  __shared__ __align__(16) unsigned short lds[16384];   // 32KB
  const int tid = threadIdx.x;
  const int l = tid & 63;
  const int w = tid >> 6;
  const int wr = w >> 1, wc = w & 1;
  const long long row0 = (long long)blockIdx.x * 128;
  const long long col0 = (long long)blockIdx.y * 128;

  fx4 acc[4][4] = {};

  const unsigned short* gA[4];
  const unsigned short* gB[4];
  int lslot[4];
  #pragma unroll
  for (int i=0;i<4;i++){
    int slot = w*256 + i*64 + l;
    int r = slot >> 3;
    int qs = slot & 7;
    int c = (qs ^ (r & 7)) << 3;
    gA[i] = A  + (row0 + r)*(long long)K + c;
    gB[i] = Bt + (col0 + r)*(long long)K + c;
    lslot[i] = slot*8;
  }
  int aoff[2][4], boff[2][4];
  #pragma unroll
  for (int kk=0;kk<2;kk++){
    #pragma unroll
    for (int m=0;m<4;m++){
      int r  = wr*64 + m*16 + (l&15);
      int q  = (kk*4 + (l>>4)) ^ (r&7);
      aoff[kk][m] = r*64 + q*8;
      int r2 = wc*64 + m*16 + (l&15);
      int q2 = (kk*4 + (l>>4)) ^ (r2&7);
      boff[kk][m] = 8192 + r2*64 + q2*8;
    }
  }

  const int nsteps = K >> 6;
  for (int s = 0; s < nsteps; ++s){
    #pragma unroll
    for (int i=0;i<4;i++){
      gload_lds16(gA[i], &lds[lslot[i]]);
      gload_lds16(gB[i], &lds[8192 + lslot[i]]);
      gA[i] += 64; gB[i] += 64;
    }
    __syncthreads();
    #pragma unroll
    for (int kk=0;kk<2;kk++){
      s16x8 af[4], bfr[4];
      #pragma unroll
      for (int m=0;m<4;m++) af[m]  = *(const s16x8*)&lds[aoff[kk][m]];
      #pragma unroll
      for (int n=0;n<4;n++) bfr[n] = *(const s16x8*)&lds[boff[kk][n]];
      #pragma unroll
      for (int m=0;m<4;m++)
        #pragma unroll
        for (int n=0;n<4;n++)
          acc[m][n] = __builtin_amdgcn_mfma_f32_16x16x32_bf16(af[m], bfr[n], acc[m][n], 0, 0, 0);
    }
    __syncthreads();
  }

  float* lf = (float*)lds;              // [32][132]
  const int lg = l >> 4, lc = l & 15;
  #pragma unroll
  for (int g=0; g<4; ++g){
    if (wr == (g>>1)){
      #pragma unroll
      for (int mm=0; mm<2; ++mm){
        const int m = (g&1)*2 + mm;
        int lrow = mm*16 + lg*4;
        #pragma unroll
        for (int n=0;n<4;n++){
          int col = wc*64 + n*16 + lc;
          #pragma unroll
          for (int rg=0;rg<4;rg++)
            lf[(lrow+rg)*132 + col] = acc[m][n][rg];
        }
      }
    }
    __syncthreads();
    #pragma unroll
    for (int j=0;j<4;j++){
      int flat = j*256 + tid;
      int lrow = flat >> 5, c4 = flat & 31;
      long long grow = row0 + g*32 + lrow;
      long long gcol = col0 + c4*4;
      fx4 v = *(fx4*)&lf[lrow*132 + c4*4];
      fx4 bv = *(const fx4*)&bias[gcol];
      v = v + bv;
      long long idx = grow*(long long)N + gcol;
      if constexpr (EPI==1){
        fx4 rv = *(const fx4*)&res[idx];
        v = v + rv;
        *(fx4*)&outf[idx] = v;
      } else {
        ushort4 pk;
        pk.x = f2bf(v[0]); pk.y = f2bf(v[1]);
        pk.z = f2bf(v[2]); pk.w = f2bf(v[3]);
        *(ushort4*)&outb[idx] = pk;
      }
    }
    __syncthreads();
  }
}

// ---------------- 128x128 FP8 GEMM, TRIPLE-buffer counted-vmcnt (r13/r14 verified) ----------------
// Best measured config: 48KB LDS (>=3 blocks/CU), wave-tile 64x64, vmcnt(4),
// swizzle pair (r>>1)&3 (0 conflicts), cvt_pk epilogue. 70us @ N=4096 path.
// r15's 128x256 wide tile (72KB LDS) collapsed occupancy to ~1 blk/CU: reverted.
// EPI 1: fp32+bias+res  2: fp8(gelu(acc/64+bias))
template<int EPI, int K>
__global__ __launch_bounds__(256) void gemm_f8(const unsigned char* __restrict__ A,
    const unsigned char* __restrict__ Bt, int N,
    const float* __restrict__ bias, const float* __restrict__ res,
    float* __restrict__ outf, unsigned char* __restrict__ outb){
  __shared__ __align__(16) unsigned char lds[49152];  // 3 x (A 8KB + B 8KB)
  const int tid = threadIdx.x;
  const int l = tid & 63;
  const int w = tid >> 6;
  const int wr = w >> 1, wc = w & 1;
  const long long row0 = (long long)blockIdx.x * 128;
  const long long col0 = (long long)blockIdx.y * 128;

  fx4 acc[4][4] = {};

  const unsigned char* gA[2];
  const unsigned char* gB[2];
  int lslot[2];
  #pragma unroll
  for (int i=0;i<2;i++){
    int slot = w*128 + i*64 + l;       // 0..511
    int r = slot >> 2;                 // row 0..127 (64B rows, 4 chunks)
    int q = slot & 3;
    int c = (q ^ ((r >> 1) & 3)) << 4; // inverse swizzle on global source
    gA[i] = A  + (row0 + r)*(long long)K + c;
    gB[i] = Bt + (col0 + r)*(long long)K + c;
    lslot[i] = slot*16;
  }
  const int lg = l >> 4, l15 = l & 15;
  int aoff[4], boff[4];
  #pragma unroll
  for (int m=0;m<4;m++){
    int r  = wr*64 + m*16 + l15;
    aoff[m] = r*64 + ((lg ^ ((r >> 1) & 3)) << 4);
    int r2 = wc*64 + m*16 + l15;
    boff[m] = 8192 + r2*64 + ((lg ^ ((r2 >> 1) & 3)) << 4);
  }
  auto STAGE = [&](int bufoff){
    #pragma unroll
    for (int i=0;i<2;i++){
      gload_lds16(gA[i], &lds[bufoff + lslot[i]]);
      gload_lds16(gB[i], &lds[bufoff + 8192 + lslot[i]]);
      gA[i] += 64; gB[i] += 64;
    }
  };

  const int nsteps = K >> 6;
  STAGE(0);
  STAGE(16384);

  int curoff = 0;
  for (int s = 0; s < nsteps; ++s){
    if (s + 1 < nsteps) asm volatile("s_waitcnt vmcnt(4)" ::: "memory");
    else                asm volatile("s_waitcnt vmcnt(0)" ::: "memory");
    __builtin_amdgcn_sched_barrier(0);
    __builtin_amdgcn_s_barrier();
    __builtin_amdgcn_sched_barrier(0);
    u64x2 a2[4], b2[4];
    #pragma unroll
    for (int m=0;m<4;m++) a2[m] = *(const u64x2*)&lds[curoff + aoff[m]];
    #pragma unroll
    for (int n=0;n<4;n++) b2[n] = *(const u64x2*)&lds[curoff + boff[n]];
    if (s + 2 < nsteps){
      int nb = curoff + 32768; if (nb >= 49152) nb -= 49152;   // buf (s+2)%3
      STAGE(nb);
    }
    #pragma unroll
    for (int m=0;m<4;m++)
      #pragma unroll
      for (int n=0;n<4;n++)
        acc[m][n] = mfma_fp8(a2[m][0], b2[n][0], acc[m][n]);
    #pragma unroll
    for (int m=0;m<4;m++)
      #pragma unroll
      for (int n=0;n<4;n++)
        acc[m][n] = mfma_fp8(a2[m][1], b2[n][1], acc[m][n]);
    curoff += 16384; if (curoff == 49152) curoff = 0;
  }
  __syncthreads();

  float* lf = (float*)lds;              // [32][132] fp32 = 16.9KB
  #pragma unroll
  for (int g=0; g<4; ++g){
    if (wr == (g>>1)){
      #pragma unroll
      for (int mm=0; mm<2; ++mm){
        const int m = (g&1)*2 + mm;
        int lrow = mm*16 + lg*4;
        #pragma unroll
        for (int n=0;n<4;n++){
          int col = wc*64 + n*16 + l15;
          #pragma unroll
          for (int rg=0;rg<4;rg++)
            lf[(lrow+rg)*132 + col] = acc[m][n][rg];
        }
      }
    }
    __syncthreads();
    #pragma unroll
    for (int j=0;j<4;j++){
      int flat = j*256 + tid;
      int lrow = flat >> 5, c4 = flat & 31;
      long long grow = row0 + g*32 + lrow;
      long long gcol = col0 + c4*4;
      fx4 v = *(fx4*)&lf[lrow*132 + c4*4];
      fx4 bv2 = *(const fx4*)&bias[gcol];
      v = v * 0.015625f + bv2;          // undo W*64
      long long idx = grow*(long long)N + gcol;
      if constexpr (EPI==1){
        fx4 rv = *(const fx4*)&res[idx];
        v = v + rv;
        *(fx4*)&outf[idx] = v;
      } else {
        *(int*)&outb[idx] = pk4_fp8(gelu_f(v[0]), gelu_f(v[1]),
                                    gelu_f(v[2]), gelu_f(v[3]));
      }
    }
    __syncthreads();
  }
}

// ---------------- host ----------------
extern "C" void kernel_launch(void* const* d_in, const int* in_sizes, int n_in,
                              void* d_out, int out_size, void* d_ws, size_t ws_size,
                              hipStream_t stream){
  const float* x    = (const float*)d_in[0];
  const float* g1   = (const float*)d_in[1];
  const float* b1   = (const float*)d_in[2];
  const float* g2   = (const float*)d_in[3];
  const float* b2   = (const float*)d_in[4];
  const float* Wp   = (const float*)d_in[5];
  const float* bp   = (const float*)d_in[6];
  const float* Wo   = (const float*)d_in[7];
  const float* bo   = (const float*)d_in[8];
  const float* w_col= (const float*)d_in[9];
  const float* b_col= (const float*)d_in[10];
  const float* w_row= (const float*)d_in[11];
  const float* b_row= (const float*)d_in[12];
  const float* dcol = (const float*)d_in[13];
  const float* drow = (const float*)d_in[14];
  const float* W1   = (const float*)d_in[15];
  const float* c1   = (const float*)d_in[16];
  const float* W2   = (const float*)d_in[17];
  const float* c2   = (const float*)d_in[18];
  float* out = (float*)d_out;

  char* ws = (char*)d_ws;
  const size_t MB = 1024*1024;
  if (ws_size < 101*MB) return;
  unsigned short* Wpt  = (unsigned short*)(ws + 0);      // 128KB bf16
  unsigned short* Wot  = (unsigned short*)(ws + 2*MB);   // 2MB bf16
  unsigned char*  W1t8 = (unsigned char*)(ws + 4*MB);    // 4MB fp8 (x64)
  unsigned char*  W2t8 = (unsigned char*)(ws + 12*MB);   // 4MB fp8 (x64)
  unsigned short* h    = (unsigned short*)(ws + 20*MB);  // 16MB bf16; later yln8
  unsigned char*  yln8 = (unsigned char*)(ws + 20*MB);   // 8MB fp8 (h dead)
  unsigned short* P    = (unsigned short*)(ws + 36*MB);  // 16MB bf16
  unsigned char*  U8   = (unsigned char*)(ws + 36*MB);   // 32MB fp8 (P/mix dead)
  unsigned short* mix  = (unsigned short*)(ws + 68*MB);  // 16MB bf16
  float*          carry= (float*)(ws + 84*MB);

  dim3 tb(32,8);
  transpose_k <<<dim3(2,32,16),  tb, 0, stream>>>(Wp, Wpt, 1024,   64, 65536LL, 65536LL);
  transpose_k <<<dim3(32,32,1),  tb, 0, stream>>>(Wo, Wot, 1024, 1024, 0LL, 0LL);
  transpose_f8<<<dim3(128,32,1), tb, 0, stream>>>(W1, W1t8, 1024, 4096);
  transpose_f8<<<dim3(32,128,1), tb, 0, stream>>>(W2, W2t8, 4096, 1024);

  ln_rows<<<dim3(ROWS), dim3(256), 0, stream>>>(x, g1, b1, h);
  gemm_bt<3,1024><<<dim3(64,8),  dim3(256), 0, stream>>>(h,   Wpt, 1024, bp, nullptr, nullptr, P);
  scan_carry<<<dim3(512), dim3(256), 0, stream>>>(P, w_row, dcol, drow, carry);
  scan_final<<<dim3(512), dim3(256), 0, stream>>>(P, w_col, b_col, w_row, b_row, dcol, drow, carry, mix);
  gemm_bt<1,1024><<<dim3(64,8),  dim3(256), 0, stream>>>(mix, Wot, 1024, bo, x, out, nullptr);
  ln_rows_f8<<<dim3(ROWS), dim3(256), 0, stream>>>(out, g2, b2, yln8);
  gemm_f8<2,1024><<<dim3(64,32), dim3(256), 0, stream>>>(yln8, W1t8, 4096, c1, nullptr, nullptr, U8);
  gemm_f8<1,4096><<<dim3(64,8),  dim3(256), 0, stream>>>(U8,  W2t8, 1024, c2, out, out, nullptr);
}

// Round 17
// 252.838 us; speedup vs baseline: 1.3019x; 1.0465x over previous
//
#include <hip/hip_runtime.h>

typedef __attribute__((ext_vector_type(4))) float fx4;
typedef __attribute__((ext_vector_type(8))) short s16x8;
typedef __attribute__((ext_vector_type(2))) unsigned long long u64x2;

#define SEQ   2048
#define DM    1024
#define BSZ   4
#define ROWS  (BSZ*SEQ)   /* 8192 */
#define CHUNK 64
#define NCH   (SEQ/CHUNK) /* 32 */

__device__ __forceinline__ unsigned short f2bf(float f){
  unsigned u = __builtin_bit_cast(unsigned, f);
  u = u + 0x7FFFu + ((u >> 16) & 1u);
  return (unsigned short)(u >> 16);
}
__device__ __forceinline__ float bf2f(unsigned short u){
  return __builtin_bit_cast(float, ((unsigned)u) << 16);
}

// f32 -> OCP e4m3fn (software path, used only in weight prepack).
__device__ __forceinline__ unsigned char f2fp8(float x){
  unsigned u = __builtin_bit_cast(unsigned, x);
  unsigned s = (u >> 24) & 0x80u;
  float ax = __builtin_fabsf(x);
  if (ax >= 448.f) return (unsigned char)(s | 0x7Eu);
  if (ax < 0.015625f){
    int m = (int)(ax * 512.f + 0.5f);
    return (unsigned char)(s | (unsigned)m);
  }
  unsigned b = __builtin_bit_cast(unsigned, ax);
  b += 0x0007FFFFu + ((b >> 20) & 1u);
  unsigned e = (b >> 23) - 127u + 7u;
  unsigned m = (b >> 20) & 7u;
  return (unsigned char)(s | (e << 3) | m);
}

// HW pack: 4 f32 -> 4 fp8 bytes in one int.
__device__ __forceinline__ int pk4_fp8(float a, float b, float c, float d){
  int lo = __builtin_amdgcn_cvt_pk_fp8_f32(a, b, 0, false);
  return  __builtin_amdgcn_cvt_pk_fp8_f32(c, d, lo, true);
}

// fast tanh-gelu: 0.5x(1+tanh(u)) == x*sigmoid(2u)
__device__ __forceinline__ float gelu_f(float x){
  float u = 0.7978845608028654f * (x + 0.044715f * x*x*x);
  return x / (1.0f + __expf(-2.0f*u));
}

__device__ __forceinline__ void gload_lds16(const void* g, void* l){
  __builtin_amdgcn_global_load_lds(
      (__attribute__((address_space(1))) void*)g,
      (__attribute__((address_space(3))) void*)l, 16, 0, 0);
}

// non-scaled fp8 MFMA (bf16 rate, 2-VGPR operands). B holds W*64.
__device__ __forceinline__ fx4 mfma_fp8(unsigned long long a, unsigned long long b, fx4 c){
  return __builtin_amdgcn_mfma_f32_16x16x32_fp8_fp8((long)a, (long)b, c, 0, 0, 0);
}

// =====================================================================
// FUSED PREPACK + first LayerNorm: one launch replaces 5 independent ones
// (4 weight transposes + ln_rows). blocks 0..8191 = LN rows; then
// Wp(1024) / Wo(1024) / W1(4096) / W2(4096) transpose tiles.
// =====================================================================
__global__ __launch_bounds__(256) void prepack_ln(
    const float* __restrict__ x,  const float* __restrict__ g1, const float* __restrict__ b1,
    unsigned short* __restrict__ h,
    const float* __restrict__ Wp, unsigned short* __restrict__ Wpt,
    const float* __restrict__ Wo, unsigned short* __restrict__ Wot,
    const float* __restrict__ W1, unsigned char*  __restrict__ W1t8,
    const float* __restrict__ W2, unsigned char*  __restrict__ W2t8){
  const int tid = threadIdx.x;
  int bid = blockIdx.x;

  if (bid < ROWS){
    // ---- LayerNorm row ----
    const int row = bid, t = tid;
    const fx4* xr = (const fx4*)(x + (long long)row*DM);
    fx4 v = xr[t];
    float s  = v[0]+v[1]+v[2]+v[3];
    float s2 = v[0]*v[0]+v[1]*v[1]+v[2]*v[2]+v[3]*v[3];
    #pragma unroll
    for (int o=32;o;o>>=1){ s += __shfl_down(s,o); s2 += __shfl_down(s2,o); }
    __shared__ float red[8];
    int lane = t & 63, wid = t >> 6;
    if (lane==0){ red[wid]=s; red[4+wid]=s2; }
    __syncthreads();
    s  = red[0]+red[1]+red[2]+red[3];
    s2 = red[4]+red[5]+red[6]+red[7];
    float m  = s * (1.0f/DM);
    float rs = rsqrtf(s2*(1.0f/DM) - m*m + 1e-5f);
    const fx4 gv = ((const fx4*)g1)[t], bv = ((const fx4*)b1)[t];
    ushort4 pk;
    pk.x = f2bf((v[0]-m)*rs*gv[0] + bv[0]);
    pk.y = f2bf((v[1]-m)*rs*gv[1] + bv[1]);
    pk.z = f2bf((v[2]-m)*rs*gv[2] + bv[2]);
    pk.w = f2bf((v[3]-m)*rs*gv[3] + bv[3]);
    *(ushort4*)(h + (long long)row*DM + t*4) = pk;
    return;
  }
  bid -= ROWS;

  // ---- 32x32 transpose tile ----
  __shared__ float tile[32][33];
  const int tx = tid & 31, ty = tid >> 5;       // 32 x 8
  const float* in; int R, C, c0, r0;
  int mode;                                      // 0: bf16 out, 1: fp8*64 out
  unsigned short* outb = nullptr;
  unsigned char*  out8 = nullptr;
  if (bid < 1024){               // Wp [16][1024][64] -> per-head [64][1024]
    int z = bid >> 6, rem = bid & 63;
    int y = rem >> 1, xq = rem & 1;
    in = Wp + (long long)z*65536; outb = Wpt + (long long)z*65536;
    R = 1024; C = 64; c0 = xq*32; r0 = y*32; mode = 0;
  } else if (bid < 2048){        // Wo [1024][1024]
    int b2 = bid - 1024;
    int xq = b2 & 31, y = b2 >> 5;
    in = Wo; outb = Wot; R = 1024; C = 1024; c0 = xq*32; r0 = y*32; mode = 0;
  } else if (bid < 6144){        // W1 [1024][4096]
    int b2 = bid - 2048;
    int xq = b2 & 127, y = b2 >> 7;
    in = W1; out8 = W1t8; R = 1024; C = 4096; c0 = xq*32; r0 = y*32; mode = 1;
  } else {                       // W2 [4096][1024]
    int b2 = bid - 6144;
    int xq = b2 & 31, y = b2 >> 5;
    in = W2; out8 = W2t8; R = 4096; C = 1024; c0 = xq*32; r0 = y*32; mode = 1;
  }
  #pragma unroll
  for (int i=0;i<4;i++)
    tile[ty+8*i][tx] = in[(long long)(r0+ty+8*i)*C + c0+tx];
  __syncthreads();
  if (mode == 0){
    #pragma unroll
    for (int i=0;i<4;i++)
      outb[(long long)(c0+ty+8*i)*R + r0+tx] = f2bf(tile[tx][ty+8*i]);
  } else {
    #pragma unroll
    for (int i=0;i<4;i++)
      out8[(long long)(c0+ty+8*i)*R + r0+tx] = f2fp8(tile[tx][ty+8*i] * 64.f);
  }
}

// ---------------- LayerNorm, fp8 out (HW cvt_pk) ----------------
__global__ __launch_bounds__(256) void ln_rows_f8(const float* __restrict__ x,
    const float* __restrict__ g, const float* __restrict__ b,
    unsigned char* __restrict__ out){
  int row = blockIdx.x, t = threadIdx.x;
  const fx4* xr = (const fx4*)(x + (long long)row*DM);
  fx4 v = xr[t];
  float s  = v[0]+v[1]+v[2]+v[3];
  float s2 = v[0]*v[0]+v[1]*v[1]+v[2]*v[2]+v[3]*v[3];
  #pragma unroll
  for (int o=32;o;o>>=1){ s += __shfl_down(s,o); s2 += __shfl_down(s2,o); }
  __shared__ float red[8];
  int lane = t & 63, wid = t >> 6;
  if (lane==0){ red[wid]=s; red[4+wid]=s2; }
  __syncthreads();
  s  = red[0]+red[1]+red[2]+red[3];
  s2 = red[4]+red[5]+red[6]+red[7];
  float m  = s * (1.0f/DM);
  float rs = rsqrtf(s2*(1.0f/DM) - m*m + 1e-5f);
  const fx4 gv = ((const fx4*)g)[t], bv = ((const fx4*)b)[t];
  int pk = pk4_fp8((v[0]-m)*rs*gv[0] + bv[0], (v[1]-m)*rs*gv[1] + bv[1],
                   (v[2]-m)*rs*gv[2] + bv[2], (v[3]-m)*rs*gv[3] + bv[3]);
  *(int*)(out + (long long)row*DM + t*4) = pk;
}

// ---------------- scan pass 1: per-chunk carries (P in bf16) ----------------
__global__ __launch_bounds__(256) void scan_carry(const unsigned short* __restrict__ P,
    const float* __restrict__ w_row, const float* __restrict__ dcol,
    const float* __restrict__ drow, float* __restrict__ carry){
  int g = blockIdx.x*4 + (threadIdx.x>>6);
  int lane = threadIdx.x & 63;
  int chunk = g & (NCH-1); int bh = g >> 5; int h = bh & 15; int b = bh >> 4;
  float draw = (h<8) ? dcol[h] : drow[h-8];
  float d = powf(fminf(fmaxf(draw,0.9f),1.0f), 0.25f);
  float c = 0.f;
  const unsigned short* p = P + ((long long)(b*SEQ + chunk*CHUNK))*DM + h*64 + lane;
  const float* wr = w_row + (h>=8 ? (h-8)*SEQ + chunk*CHUNK : 0);
  #pragma unroll 4
  for (int i=0;i<CHUNK;i++){
    float a = bf2f(p[(long long)i*DM]);
    if (h>=8) a *= wr[i];
    c = fmaf(d, c, a);
  }
  carry[((long long)(bh*64 + lane))*NCH + chunk] = c;
}

// ---------------- scan pass 2: apply carries, emit mix (bf16) ----------------
__global__ __launch_bounds__(256) void scan_final(const unsigned short* __restrict__ P,
    const float* __restrict__ w_col, const float* __restrict__ b_col,
    const float* __restrict__ w_row, const float* __restrict__ b_row,
    const float* __restrict__ dcol, const float* __restrict__ drow,
    const float* __restrict__ carry, unsigned short* __restrict__ mix){
  int g = blockIdx.x*4 + (threadIdx.x>>6);
  int lane = threadIdx.x & 63;
  int chunk = g & (NCH-1); int bh = g >> 5; int h = bh & 15; int b = bh >> 4;
  float draw = (h<8) ? dcol[h] : drow[h-8];
  float d = powf(fminf(fmaxf(draw,0.9f),1.0f), 0.25f);
  float dL = d;
  #pragma unroll
  for (int i=0;i<6;i++) dL *= dL;        // d^64
  const float* cr = carry + ((long long)(bh*64 + lane))*NCH;
  float c = 0.f;
  for (int j=0;j<chunk;j++) c = fmaf(dL, c, cr[j]);   // carry-in
  const unsigned short* p = P + ((long long)(b*SEQ + chunk*CHUNK))*DM + h*64 + lane;
  unsigned short* mo = mix + ((long long)(b*SEQ + chunk*CHUNK))*DM + h*64 + lane;
  int t0 = chunk*CHUNK;
  #pragma unroll 4
  for (int i=0;i<CHUNK;i++){
    int t = t0 + i;
    float a = bf2f(p[(long long)i*DM]);
    float o;
    if (h<8){
      c = fmaf(d, c, a);
      o = w_col[h*SEQ + t]*c + b_col[h*SEQ + t];
    } else {
      a *= w_row[(h-8)*SEQ + t];
      c = fmaf(d, c, a);
      o = c + b_row[(h-8)*SEQ + t];
    }
    mo[(long long)i*DM] = f2bf(o);
  }
}

// ---------------- 128x128 bf16 GEMM, single 32KB buffer, BK=64 (r11 verified) ----------------
// EPI 1: fp32+bias+res  3: bf16
template<int EPI, int K>
__global__ __launch_bounds__(256) void gemm_bt(const unsigned short* __restrict__ A,
    const unsigned short* __restrict__ Bt, int N,
    const float* __restrict__ bias, const float* __restrict__ res,
    float* __restrict__ outf, unsigned short* __restrict__ outb){
  __shared__ __align__(16) unsigned short lds[16384];   // 32KB
  const int tid = threadIdx.x;
  const int l = tid & 63;
  const int w = tid >> 6;
  const int wr = w >> 1, wc = w & 1;
  const long long row0 = (long long)blockIdx.x * 128;
  const long long col0 = (long long)blockIdx.y * 128;

  fx4 acc[4][4] = {};

  const unsigned short* gA[4];
  const unsigned short* gB[4];
  int lslot[4];
  #pragma unroll
  for (int i=0;i<4;i++){
    int slot = w*256 + i*64 + l;
    int r = slot >> 3;
    int qs = slot & 7;
    int c = (qs ^ (r & 7)) << 3;
    gA[i] = A  + (row0 + r)*(long long)K + c;
    gB[i] = Bt + (col0 + r)*(long long)K + c;
    lslot[i] = slot*8;
  }
  int aoff[2][4], boff[2][4];
  #pragma unroll
  for (int kk=0;kk<2;kk++){
    #pragma unroll
    for (int m=0;m<4;m++){
      int r  = wr*64 + m*16 + (l&15);
      int q  = (kk*4 + (l>>4)) ^ (r&7);
      aoff[kk][m] = r*64 + q*8;
      int r2 = wc*64 + m*16 + (l&15);
      int q2 = (kk*4 + (l>>4)) ^ (r2&7);
      boff[kk][m] = 8192 + r2*64 + q2*8;
    }
  }

  const int nsteps = K >> 6;
  for (int s = 0; s < nsteps; ++s){
    #pragma unroll
    for (int i=0;i<4;i++){
      gload_lds16(gA[i], &lds[lslot[i]]);
      gload_lds16(gB[i], &lds[8192 + lslot[i]]);
      gA[i] += 64; gB[i] += 64;
    }
    __syncthreads();
    #pragma unroll
    for (int kk=0;kk<2;kk++){
      s16x8 af[4], bfr[4];
      #pragma unroll
      for (int m=0;m<4;m++) af[m]  = *(const s16x8*)&lds[aoff[kk][m]];
      #pragma unroll
      for (int n=0;n<4;n++) bfr[n] = *(const s16x8*)&lds[boff[kk][n]];
      #pragma unroll
      for (int m=0;m<4;m++)
        #pragma unroll
        for (int n=0;n<4;n++)
          acc[m][n] = __builtin_amdgcn_mfma_f32_16x16x32_bf16(af[m], bfr[n], acc[m][n], 0, 0, 0);
    }
    __syncthreads();
  }

  float* lf = (float*)lds;              // [32][132]
  const int lg = l >> 4, lc = l & 15;
  #pragma unroll
  for (int g=0; g<4; ++g){
    if (wr == (g>>1)){
      #pragma unroll
      for (int mm=0; mm<2; ++mm){
        const int m = (g&1)*2 + mm;
        int lrow = mm*16 + lg*4;
        #pragma unroll
        for (int n=0;n<4;n++){
          int col = wc*64 + n*16 + lc;
          #pragma unroll
          for (int rg=0;rg<4;rg++)
            lf[(lrow+rg)*132 + col] = acc[m][n][rg];
        }
      }
    }
    __syncthreads();
    #pragma unroll
    for (int j=0;j<4;j++){
      int flat = j*256 + tid;
      int lrow = flat >> 5, c4 = flat & 31;
      long long grow = row0 + g*32 + lrow;
      long long gcol = col0 + c4*4;
      fx4 v = *(fx4*)&lf[lrow*132 + c4*4];
      fx4 bv = *(const fx4*)&bias[gcol];
      v = v + bv;
      long long idx = grow*(long long)N + gcol;
      if constexpr (EPI==1){
        fx4 rv = *(const fx4*)&res[idx];
        v = v + rv;
        *(fx4*)&outf[idx] = v;
      } else {
        ushort4 pk;
        pk.x = f2bf(v[0]); pk.y = f2bf(v[1]);
        pk.z = f2bf(v[2]); pk.w = f2bf(v[3]);
        *(ushort4*)&outb[idx] = pk;
      }
    }
    __syncthreads();
  }
}

// ---------------- 128x128 FP8 GEMM, TRIPLE-buffer counted-vmcnt (r13/r14/r16 verified) ----------------
// 48KB LDS (3 blocks/CU), wave-tile 64x64, vmcnt(4), swizzle pair (r>>1)&3
// (0 conflicts), cvt_pk epilogue. 69.5us each @ MfmaUtil 40% = 95% of the
// structural LDS-BW ceiling (43%) of this geometry.
// EPI 1: fp32+bias+res  2: fp8(gelu(acc/64+bias))
template<int EPI, int K>
__global__ __launch_bounds__(256) void gemm_f8(const unsigned char* __restrict__ A,
    const unsigned char* __restrict__ Bt, int N,
    const float* __restrict__ bias, const float* __restrict__ res,
    float* __restrict__ outf, unsigned char* __restrict__ outb){
  __shared__ __align__(16) unsigned char lds[49152];  // 3 x (A 8KB + B 8KB)
  const int tid = threadIdx.x;
  const int l = tid & 63;
  const int w = tid >> 6;
  const int wr = w >> 1, wc = w & 1;
  const long long row0 = (long long)blockIdx.x * 128;
  const long long col0 = (long long)blockIdx.y * 128;

  fx4 acc[4][4] = {};

  const unsigned char* gA[2];
  const unsigned char* gB[2];
  int lslot[2];
  #pragma unroll
  for (int i=0;i<2;i++){
    int slot = w*128 + i*64 + l;       // 0..511
    int r = slot >> 2;                 // row 0..127 (64B rows, 4 chunks)
    int q = slot & 3;
    int c = (q ^ ((r >> 1) & 3)) << 4; // inverse swizzle on global source
    gA[i] = A  + (row0 + r)*(long long)K + c;
    gB[i] = Bt + (col0 + r)*(long long)K + c;
    lslot[i] = slot*16;
  }
  const int lg = l >> 4, l15 = l & 15;
  int aoff[4], boff[4];
  #pragma unroll
  for (int m=0;m<4;m++){
    int r  = wr*64 + m*16 + l15;
    aoff[m] = r*64 + ((lg ^ ((r >> 1) & 3)) << 4);
    int r2 = wc*64 + m*16 + l15;
    boff[m] = 8192 + r2*64 + ((lg ^ ((r2 >> 1) & 3)) << 4);
  }
  auto STAGE = [&](int bufoff){
    #pragma unroll
    for (int i=0;i<2;i++){
      gload_lds16(gA[i], &lds[bufoff + lslot[i]]);
      gload_lds16(gB[i], &lds[bufoff + 8192 + lslot[i]]);
      gA[i] += 64; gB[i] += 64;
    }
  };

  const int nsteps = K >> 6;
  STAGE(0);
  STAGE(16384);

  int curoff = 0;
  for (int s = 0; s < nsteps; ++s){
    if (s + 1 < nsteps) asm volatile("s_waitcnt vmcnt(4)" ::: "memory");
    else                asm volatile("s_waitcnt vmcnt(0)" ::: "memory");
    __builtin_amdgcn_sched_barrier(0);
    __builtin_amdgcn_s_barrier();
    __builtin_amdgcn_sched_barrier(0);
    u64x2 a2[4], b2[4];
    #pragma unroll
    for (int m=0;m<4;m++) a2[m] = *(const u64x2*)&lds[curoff + aoff[m]];
    #pragma unroll
    for (int n=0;n<4;n++) b2[n] = *(const u64x2*)&lds[curoff + boff[n]];
    if (s + 2 < nsteps){
      int nb = curoff + 32768; if (nb >= 49152) nb -= 49152;   // buf (s+2)%3
      STAGE(nb);
    }
    #pragma unroll
    for (int m=0;m<4;m++)
      #pragma unroll
      for (int n=0;n<4;n++)
        acc[m][n] = mfma_fp8(a2[m][0], b2[n][0], acc[m][n]);
    #pragma unroll
    for (int m=0;m<4;m++)
      #pragma unroll
      for (int n=0;n<4;n++)
        acc[m][n] = mfma_fp8(a2[m][1], b2[n][1], acc[m][n]);
    curoff += 16384; if (curoff == 49152) curoff = 0;
  }
  __syncthreads();

  float* lf = (float*)lds;              // [32][132] fp32 = 16.9KB
  #pragma unroll
  for (int g=0; g<4; ++g){
    if (wr == (g>>1)){
      #pragma unroll
      for (int mm=0; mm<2; ++mm){
        const int m = (g&1)*2 + mm;
        int lrow = mm*16 + lg*4;
        #pragma unroll
        for (int n=0;n<4;n++){
          int col = wc*64 + n*16 + l15;
          #pragma unroll
          for (int rg=0;rg<4;rg++)
            lf[(lrow+rg)*132 + col] = acc[m][n][rg];
        }
      }
    }
    __syncthreads();
    #pragma unroll
    for (int j=0;j<4;j++){
      int flat = j*256 + tid;
      int lrow = flat >> 5, c4 = flat & 31;
      long long grow = row0 + g*32 + lrow;
      long long gcol = col0 + c4*4;
      fx4 v = *(fx4*)&lf[lrow*132 + c4*4];
      fx4 bv2 = *(const fx4*)&bias[gcol];
      v = v * 0.015625f + bv2;          // undo W*64
      long long idx = grow*(long long)N + gcol;
      if constexpr (EPI==1){
        fx4 rv = *(const fx4*)&res[idx];
        v = v + rv;
        *(fx4*)&outf[idx] = v;
      } else {
        *(int*)&outb[idx] = pk4_fp8(gelu_f(v[0]), gelu_f(v[1]),
                                    gelu_f(v[2]), gelu_f(v[3]));
      }
    }
    __syncthreads();
  }
}

// ---------------- host ----------------
extern "C" void kernel_launch(void* const* d_in, const int* in_sizes, int n_in,
                              void* d_out, int out_size, void* d_ws, size_t ws_size,
                              hipStream_t stream){
  const float* x    = (const float*)d_in[0];
  const float* g1   = (const float*)d_in[1];
  const float* b1   = (const float*)d_in[2];
  const float* g2   = (const float*)d_in[3];
  const float* b2   = (const float*)d_in[4];
  const float* Wp   = (const float*)d_in[5];
  const float* bp   = (const float*)d_in[6];
  const float* Wo   = (const float*)d_in[7];
  const float* bo   = (const float*)d_in[8];
  const float* w_col= (const float*)d_in[9];
  const float* b_col= (const float*)d_in[10];
  const float* w_row= (const float*)d_in[11];
  const float* b_row= (const float*)d_in[12];
  const float* dcol = (const float*)d_in[13];
  const float* drow = (const float*)d_in[14];
  const float* W1   = (const float*)d_in[15];
  const float* c1   = (const float*)d_in[16];
  const float* W2   = (const float*)d_in[17];
  const float* c2   = (const float*)d_in[18];
  float* out = (float*)d_out;

  char* ws = (char*)d_ws;
  const size_t MB = 1024*1024;
  if (ws_size < 101*MB) return;
  unsigned short* Wpt  = (unsigned short*)(ws + 0);      // 128KB bf16
  unsigned short* Wot  = (unsigned short*)(ws + 2*MB);   // 2MB bf16
  unsigned char*  W1t8 = (unsigned char*)(ws + 4*MB);    // 4MB fp8 (x64)
  unsigned char*  W2t8 = (unsigned char*)(ws + 12*MB);   // 4MB fp8 (x64)
  unsigned short* h    = (unsigned short*)(ws + 20*MB);  // 16MB bf16; later yln8
  unsigned char*  yln8 = (unsigned char*)(ws + 20*MB);   // 8MB fp8 (h dead)
  unsigned short* P    = (unsigned short*)(ws + 36*MB);  // 16MB bf16
  unsigned char*  U8   = (unsigned char*)(ws + 36*MB);   // 32MB fp8 (P/mix dead)
  unsigned short* mix  = (unsigned short*)(ws + 68*MB);  // 16MB bf16
  float*          carry= (float*)(ws + 84*MB);

  // fused: 4 weight transposes + first LN (all independent) in ONE launch
  prepack_ln<<<dim3(ROWS + 10240), dim3(256), 0, stream>>>(
      x, g1, b1, h, Wp, Wpt, Wo, Wot, W1, W1t8, W2, W2t8);

  gemm_bt<3,1024><<<dim3(64,8),  dim3(256), 0, stream>>>(h,   Wpt, 1024, bp, nullptr, nullptr, P);
  scan_carry<<<dim3(512), dim3(256), 0, stream>>>(P, w_row, dcol, drow, carry);
  scan_final<<<dim3(512), dim3(256), 0, stream>>>(P, w_col, b_col, w_row, b_row, dcol, drow, carry, mix);
  gemm_bt<1,1024><<<dim3(64,8),  dim3(256), 0, stream>>>(mix, Wot, 1024, bo, x, out, nullptr);
  ln_rows_f8<<<dim3(ROWS), dim3(256), 0, stream>>>(out, g2, b2, yln8);
  gemm_f8<2,1024><<<dim3(64,32), dim3(256), 0, stream>>>(yln8, W1t8, 4096, c1, nullptr, nullptr, U8);
  gemm_f8<1,4096><<<dim3(64,8),  dim3(256), 0, stream>>>(U8,  W2t8, 1024, c2, out, out, nullptr);
}